// Round 1
// baseline (775.369 us; speedup 1.0000x reference)
//
#include <hip/hip_runtime.h>

typedef _Float16 f16;
typedef _Float16 f16x8 __attribute__((ext_vector_type(8)));
typedef float f32x4 __attribute__((ext_vector_type(4)));

#define KM 0.1f   // DT * TAU_MEM_INV
#define KS 0.8f   // 1 - DT * TAU_SYN_INV

// ---------- weight prep: fp32 -> f16 hi + f16 (lo*4096), zero-padded to [Np,Kp] ----------
__global__ void prep_w(const float* __restrict__ W, f16* __restrict__ hi, f16* __restrict__ lo,
                       int Nr, int Kr, int Kp, int total) {
  int i = blockIdx.x * 256 + threadIdx.x;
  if (i >= total) return;
  int o = i / Kp, f = i - o * Kp;
  float w = 0.f;
  if (o < Nr && f < Kr) w = W[(size_t)o * Kr + f];
  f16 h = (f16)w;
  float hf = (float)h;
  if (__builtin_fabsf(hf) < 6.103515625e-05f) { h = (f16)0.f; hf = 0.f; }  // avoid f16-denorm hi
  f16 l = (f16)((w - hf) * 4096.0f);
  hi[i] = h;
  lo[i] = l;
}

// ---------- encoder (voltage-only LIF) + LIF0, elementwise over (b,f), scan over t ----------
__global__ void enc_lif0(const float* __restrict__ img, f16* __restrict__ S0) {
  int idx = blockIdx.x * 256 + threadIdx.x;
  if (idx >= 128 * 12032) return;
  int b = idx / 12032, f = idx - b * 12032;
  float x = (f < 12000) ? img[b * 12000 + f] : 0.f;
  float ve = 0.f, vl = 0.f, il = 0.f;
  size_t base = (size_t)b * 12032 + f;
  for (int t = 0; t < 32; ++t) {
    // encoder step
    ve = ve + KM * (x - ve);
    float z0 = (ve > 1.0f) ? 1.f : 0.f;
    ve = ve - z0 * ve;
    // LIF0 step (spike computed from pre-input state)
    float vdec = vl + KM * (il - vl);
    float idec = KS * il;
    float z1 = (vdec > 1.0f) ? 1.f : 0.f;
    vl = (1.f - z1) * vdec;
    il = idec + z0;
    S0[base + (size_t)t * (128 * 12032)] = (f16)z1;
  }
}

// ---------- GEMM: C[M,Np] = A[M,Kp] @ (Whi + 2^-12 Wlo)[Np,Kp]^T, fp32 acc ----------
__launch_bounds__(256, 2)
__global__ void gemm_hilo(const f16* __restrict__ A, const f16* __restrict__ Bh,
                          const f16* __restrict__ Bl, float* __restrict__ C,
                          int Kp, int Np) {
  __shared__ f16 sA[128 * 64];
  __shared__ f16 sBh[128 * 64];
  __shared__ f16 sBl[128 * 64];
  const int tid = threadIdx.x;
  const int lane = tid & 63;
  const int wave = tid >> 6;
  const int wr = wave >> 1, wc = wave & 1;  // 2x2 waves, each 64x64
  const int m0 = blockIdx.y * 128, n0 = blockIdx.x * 128;

  f32x4 zero = {0.f, 0.f, 0.f, 0.f};
  f32x4 ah[4][4], al[4][4];
#pragma unroll
  for (int m = 0; m < 4; ++m)
#pragma unroll
    for (int n = 0; n < 4; ++n) { ah[m][n] = zero; al[m][n] = zero; }

  const int nkt = Kp >> 6;
  for (int kt = 0; kt < nkt; ++kt) {
    __syncthreads();
    const f16* Ab = A + (size_t)m0 * Kp + (size_t)kt * 64;
    const f16* Bhb = Bh + (size_t)n0 * Kp + (size_t)kt * 64;
    const f16* Blb = Bl + (size_t)n0 * Kp + (size_t)kt * 64;
#pragma unroll
    for (int j = 0; j < 4; ++j) {
      int q = j * 256 + tid;
      int r = q >> 3, c0 = (q & 7) * 8;
      __builtin_amdgcn_global_load_lds(
          (const __attribute__((address_space(1))) void*)(Ab + (size_t)r * Kp + c0),
          (__attribute__((address_space(3))) void*)(&sA[q * 8]), 16, 0, 0);
      __builtin_amdgcn_global_load_lds(
          (const __attribute__((address_space(1))) void*)(Bhb + (size_t)r * Kp + c0),
          (__attribute__((address_space(3))) void*)(&sBh[q * 8]), 16, 0, 0);
      __builtin_amdgcn_global_load_lds(
          (const __attribute__((address_space(1))) void*)(Blb + (size_t)r * Kp + c0),
          (__attribute__((address_space(3))) void*)(&sBl[q * 8]), 16, 0, 0);
    }
    __syncthreads();
#pragma unroll
    for (int kk = 0; kk < 2; ++kk) {
      const int lr = lane & 15;
      const int lk = kk * 32 + ((lane >> 4) << 3);
      f16x8 af[4], bhf[4], blf[4];
#pragma unroll
      for (int m = 0; m < 4; ++m)
        af[m] = *(const f16x8*)&sA[(wr * 64 + m * 16 + lr) * 64 + lk];
#pragma unroll
      for (int n = 0; n < 4; ++n) {
        bhf[n] = *(const f16x8*)&sBh[(wc * 64 + n * 16 + lr) * 64 + lk];
        blf[n] = *(const f16x8*)&sBl[(wc * 64 + n * 16 + lr) * 64 + lk];
      }
#pragma unroll
      for (int m = 0; m < 4; ++m)
#pragma unroll
        for (int n = 0; n < 4; ++n) {
          ah[m][n] = __builtin_amdgcn_mfma_f32_16x16x32_f16(af[m], bhf[n], ah[m][n], 0, 0, 0);
          al[m][n] = __builtin_amdgcn_mfma_f32_16x16x32_f16(af[m], blf[n], al[m][n], 0, 0, 0);
        }
    }
  }
  const int lr = lane & 15, lq = lane >> 4;
#pragma unroll
  for (int m = 0; m < 4; ++m)
#pragma unroll
    for (int n = 0; n < 4; ++n) {
      int col = n0 + wc * 64 + n * 16 + lr;
#pragma unroll
      for (int i = 0; i < 4; ++i) {
        int row = m0 + wr * 64 + m * 16 + lq * 4 + i;
        C[(size_t)row * Np + col] = ah[m][n][i] + 2.44140625e-4f * al[m][n][i];
      }
    }
}

// ---------- LI_k (on GEMM out) + LIF_{k+1} -> next spikes, elementwise over (b,n) ----------
__global__ void li_lif(const float* __restrict__ G, f16* __restrict__ Sn, int Np) {
  int idx = blockIdx.x * 256 + threadIdx.x;
  if (idx >= 128 * Np) return;
  int b = idx / Np, n = idx - b * Np;
  size_t base = (size_t)b * Np + n;
  size_t stride = (size_t)128 * Np;
  float vL = 0.f, iL = 0.f, vF = 0.f, iF = 0.f;
  for (int t = 0; t < 32; ++t) {
    float g = G[base + t * stride];
    float ij = iL + g;          // i_jump = i + inp@W^T
    vL = vL + KM * (ij - vL);   // v_new (LI output)
    iL = KS * ij;
    // LIF_{k+1}
    float vdec = vF + KM * (iF - vF);
    float idec = KS * iF;
    float z = (vdec > 1.0f) ? 1.f : 0.f;
    vF = (1.f - z) * vdec;
    iF = idec + vL;
    Sn[base + t * stride] = (f16)z;
  }
}

// ---------- LI5 scan + max over t + log_softmax ----------
__global__ void final_k(const float* __restrict__ G, float* __restrict__ out) {
  int b = blockIdx.x;   // 128
  int n = threadIdx.x;  // 64 lanes, n<10 meaningful
  float vL = 0.f, iL = 0.f, mx = -3.4e38f;
  for (int t = 0; t < 32; ++t) {
    float g = G[(size_t)(t * 128 + b) * 128 + n];
    float ij = iL + g;
    vL = vL + KM * (ij - vL);
    iL = KS * ij;
    mx = fmaxf(mx, vL);
  }
  float v = (n < 10) ? mx : -3.4e38f;
  float M = v;
#pragma unroll
  for (int s = 1; s < 16; s <<= 1) M = fmaxf(M, __shfl_xor(M, s));
  float e = (n < 10) ? expf(v - M) : 0.f;
  float sum = e;
#pragma unroll
  for (int s = 1; s < 16; s <<= 1) sum += __shfl_xor(sum, s);
  if (n < 10) out[b * 10 + n] = v - M - logf(sum);
}

extern "C" void kernel_launch(void* const* d_in, const int* in_sizes, int n_in,
                              void* d_out, int out_size, void* d_ws, size_t ws_size,
                              hipStream_t stream) {
  const float* img = (const float*)d_in[0];
  static const int Nr[6]  = {2000, 1500, 1000, 500, 100, 10};
  static const int Kr[6]  = {12000, 2000, 1500, 1000, 500, 100};
  static const int Npd[6] = {2048, 1536, 1024, 512, 128, 128};
  static const int Kpd[6] = {12032, 2048, 1536, 1024, 512, 128};

  char* p = (char*)d_ws;
  f16* whi[6];
  f16* wlo[6];
  for (int k = 0; k < 6; ++k) {
    whi[k] = (f16*)p; p += (size_t)Npd[k] * Kpd[k] * 2;
    wlo[k] = (f16*)p; p += (size_t)Npd[k] * Kpd[k] * 2;
  }
  f16* S = (f16*)p;  p += (size_t)4096 * 12032 * 2;  // shared spike buffer (max width layer 0)
  float* G = (float*)p;                              // shared GEMM-out buffer (max 4096x2048 f32)

  for (int k = 0; k < 6; ++k) {
    int total = Npd[k] * Kpd[k];
    prep_w<<<(total + 255) / 256, 256, 0, stream>>>(
        (const float*)d_in[k + 1], whi[k], wlo[k], Nr[k], Kr[k], Kpd[k], total);
  }
  enc_lif0<<<(128 * 12032) / 256, 256, 0, stream>>>(img, S);
  for (int k = 0; k < 6; ++k) {
    gemm_hilo<<<dim3(Npd[k] / 128, 32), dim3(256), 0, stream>>>(
        S, whi[k], wlo[k], G, Kpd[k], Npd[k]);
    if (k < 5)
      li_lif<<<(128 * Npd[k]) / 256, 256, 0, stream>>>(G, S, Npd[k]);
  }
  final_k<<<128, 64, 0, stream>>>(G, (float*)d_out);
}

// Round 2
// 641.361 us; speedup vs baseline: 1.2089x; 1.2089x over previous
//
#include <hip/hip_runtime.h>

typedef _Float16 f16;
typedef _Float16 f16x8 __attribute__((ext_vector_type(8)));
typedef float f32x4 __attribute__((ext_vector_type(4)));

#define KM 0.1f   // DT * TAU_MEM_INV
#define KS 0.8f   // 1 - DT * TAU_SYN_INV

// ---------- weight prep: fp32 -> f16 hi + f16 (lo*4096), zero-padded to [Np,Kp] ----------
__global__ void prep_w(const float* __restrict__ W, f16* __restrict__ hi, f16* __restrict__ lo,
                       int Nr, int Kr, int Kp, int total) {
  int i = blockIdx.x * 256 + threadIdx.x;
  if (i >= total) return;
  int o = i / Kp, f = i - o * Kp;
  float w = 0.f;
  if (o < Nr && f < Kr) w = W[(size_t)o * Kr + f];
  f16 h = (f16)w;
  float hf = (float)h;
  if (__builtin_fabsf(hf) < 6.103515625e-05f) { h = (f16)0.f; hf = 0.f; }  // avoid f16-denorm hi
  f16 l = (f16)((w - hf) * 4096.0f);
  hi[i] = h;
  lo[i] = l;
}

// ---------- encoder (voltage-only LIF) + LIF0, elementwise over (b,f), scan over t ----------
__global__ void enc_lif0(const float* __restrict__ img, f16* __restrict__ S0) {
  int idx = blockIdx.x * 256 + threadIdx.x;
  if (idx >= 128 * 12032) return;
  int b = idx / 12032, f = idx - b * 12032;
  float x = (f < 12000) ? img[b * 12000 + f] : 0.f;
  float ve = 0.f, vl = 0.f, il = 0.f;
  size_t base = (size_t)b * 12032 + f;
  for (int t = 0; t < 32; ++t) {
    ve = ve + KM * (x - ve);
    float z0 = (ve > 1.0f) ? 1.f : 0.f;
    ve = ve - z0 * ve;
    float vdec = vl + KM * (il - vl);
    float idec = KS * il;
    float z1 = (vdec > 1.0f) ? 1.f : 0.f;
    vl = (1.f - z1) * vdec;
    il = idec + z0;
    S0[base + (size_t)t * (128 * 12032)] = (f16)z1;
  }
}

// ---------- GEMM: C[M,Np] = A[M,Kp] @ (Whi + 2^-12 Wlo)[Np,Kp]^T, fp32 acc ----------
// LDS tiles are chunk-swizzled: 16B chunk slot cs of row r holds global chunk cs^(r&7).
// global_load_lds writes linearly, so the *source* column is pre-swizzled (rule #21).
__launch_bounds__(256, 2)
__global__ void gemm_hilo(const f16* __restrict__ A, const f16* __restrict__ Bh,
                          const f16* __restrict__ Bl, float* __restrict__ C,
                          int Kp, int Np) {
  __shared__ f16 sA[128 * 64];
  __shared__ f16 sBh[128 * 64];
  __shared__ f16 sBl[128 * 64];
  const int tid = threadIdx.x;
  const int lane = tid & 63;
  const int wave = tid >> 6;
  const int wr = wave >> 1, wc = wave & 1;  // 2x2 waves, each 64x64

  // XCD-chunked bijective block swizzle (all grids have nwg % 8 == 0)
  const int nx = gridDim.x;
  const int flat = blockIdx.y * nx + blockIdx.x;
  const int cpx = (nx * gridDim.y) >> 3;
  const int id = (flat & 7) * cpx + (flat >> 3);
  const int m0 = (id / nx) * 128, n0 = (id % nx) * 128;

  f32x4 zero = {0.f, 0.f, 0.f, 0.f};
  f32x4 ah[4][4], al[4][4];
#pragma unroll
  for (int m = 0; m < 4; ++m)
#pragma unroll
    for (int n = 0; n < 4; ++n) { ah[m][n] = zero; al[m][n] = zero; }

  const int nkt = Kp >> 6;
  for (int kt = 0; kt < nkt; ++kt) {
    __syncthreads();
    const f16* Ab = A + (size_t)m0 * Kp + (size_t)kt * 64;
    const f16* Bhb = Bh + (size_t)n0 * Kp + (size_t)kt * 64;
    const f16* Blb = Bl + (size_t)n0 * Kp + (size_t)kt * 64;
#pragma unroll
    for (int j = 0; j < 4; ++j) {
      int q = j * 256 + tid;
      int r = q >> 3;
      int c0 = ((q & 7) ^ (r & 7)) * 8;  // pre-swizzled source chunk
      __builtin_amdgcn_global_load_lds(
          (const __attribute__((address_space(1))) void*)(Ab + (size_t)r * Kp + c0),
          (__attribute__((address_space(3))) void*)(&sA[q * 8]), 16, 0, 0);
      __builtin_amdgcn_global_load_lds(
          (const __attribute__((address_space(1))) void*)(Bhb + (size_t)r * Kp + c0),
          (__attribute__((address_space(3))) void*)(&sBh[q * 8]), 16, 0, 0);
      __builtin_amdgcn_global_load_lds(
          (const __attribute__((address_space(1))) void*)(Blb + (size_t)r * Kp + c0),
          (__attribute__((address_space(3))) void*)(&sBl[q * 8]), 16, 0, 0);
    }
    __syncthreads();
#pragma unroll
    for (int kk = 0; kk < 2; ++kk) {
      const int lr = lane & 15;
      const int hq = lane >> 4;  // chunk index within K-tile: kk*4 + hq
      f16x8 af[4], bhf[4], blf[4];
#pragma unroll
      for (int m = 0; m < 4; ++m) {
        int R = wr * 64 + m * 16 + lr;
        int ch = (kk * 4 + hq) ^ (R & 7);  // swizzled read slot
        af[m] = *(const f16x8*)&sA[R * 64 + ch * 8];
      }
#pragma unroll
      for (int n = 0; n < 4; ++n) {
        int R = wc * 64 + n * 16 + lr;
        int ch = (kk * 4 + hq) ^ (R & 7);
        bhf[n] = *(const f16x8*)&sBh[R * 64 + ch * 8];
        blf[n] = *(const f16x8*)&sBl[R * 64 + ch * 8];
      }
#pragma unroll
      for (int m = 0; m < 4; ++m)
#pragma unroll
        for (int n = 0; n < 4; ++n) {
          ah[m][n] = __builtin_amdgcn_mfma_f32_16x16x32_f16(af[m], bhf[n], ah[m][n], 0, 0, 0);
          al[m][n] = __builtin_amdgcn_mfma_f32_16x16x32_f16(af[m], blf[n], al[m][n], 0, 0, 0);
        }
    }
  }
  const int lr = lane & 15, lq = lane >> 4;
#pragma unroll
  for (int m = 0; m < 4; ++m)
#pragma unroll
    for (int n = 0; n < 4; ++n) {
      int col = n0 + wc * 64 + n * 16 + lr;
#pragma unroll
      for (int i = 0; i < 4; ++i) {
        int row = m0 + wr * 64 + m * 16 + lq * 4 + i;
        C[(size_t)row * Np + col] = ah[m][n][i] + 2.44140625e-4f * al[m][n][i];
      }
    }
}

// ---------- LI_k (on GEMM out) + LIF_{k+1} -> next spikes, elementwise over (b,n) ----------
__global__ void li_lif(const float* __restrict__ G, f16* __restrict__ Sn, int Np) {
  int idx = blockIdx.x * 256 + threadIdx.x;
  if (idx >= 128 * Np) return;
  int b = idx / Np, n = idx - b * Np;
  size_t base = (size_t)b * Np + n;
  size_t stride = (size_t)128 * Np;
  float vL = 0.f, iL = 0.f, vF = 0.f, iF = 0.f;
  for (int t = 0; t < 32; ++t) {
    float g = G[base + t * stride];
    float ij = iL + g;
    vL = vL + KM * (ij - vL);
    iL = KS * ij;
    float vdec = vF + KM * (iF - vF);
    float idec = KS * iF;
    float z = (vdec > 1.0f) ? 1.f : 0.f;
    vF = (1.f - z) * vdec;
    iF = idec + vL;
    Sn[base + t * stride] = (f16)z;
  }
}

// ---------- LI5 scan + max over t + log_softmax ----------
__global__ void final_k(const float* __restrict__ G, float* __restrict__ out) {
  int b = blockIdx.x;
  int n = threadIdx.x;
  float vL = 0.f, iL = 0.f, mx = -3.4e38f;
  for (int t = 0; t < 32; ++t) {
    float g = G[(size_t)(t * 128 + b) * 128 + n];
    float ij = iL + g;
    vL = vL + KM * (ij - vL);
    iL = KS * ij;
    mx = fmaxf(mx, vL);
  }
  float v = (n < 10) ? mx : -3.4e38f;
  float M = v;
#pragma unroll
  for (int s = 1; s < 16; s <<= 1) M = fmaxf(M, __shfl_xor(M, s));
  float e = (n < 10) ? expf(v - M) : 0.f;
  float sum = e;
#pragma unroll
  for (int s = 1; s < 16; s <<= 1) sum += __shfl_xor(sum, s);
  if (n < 10) out[b * 10 + n] = v - M - logf(sum);
}

extern "C" void kernel_launch(void* const* d_in, const int* in_sizes, int n_in,
                              void* d_out, int out_size, void* d_ws, size_t ws_size,
                              hipStream_t stream) {
  const float* img = (const float*)d_in[0];
  static const int Nr[6]  = {2000, 1500, 1000, 500, 100, 10};
  static const int Kr[6]  = {12000, 2000, 1500, 1000, 500, 100};
  static const int Npd[6] = {2048, 1536, 1024, 512, 128, 128};
  static const int Kpd[6] = {12032, 2048, 1536, 1024, 512, 128};

  char* p = (char*)d_ws;
  f16* whi[6];
  f16* wlo[6];
  for (int k = 0; k < 6; ++k) {
    whi[k] = (f16*)p; p += (size_t)Npd[k] * Kpd[k] * 2;
    wlo[k] = (f16*)p; p += (size_t)Npd[k] * Kpd[k] * 2;
  }
  f16* S = (f16*)p;  p += (size_t)4096 * 12032 * 2;  // spike buffer (max width layer 0)
  float* G = (float*)p;                              // GEMM-out buffer (max 4096x2048 f32)

  for (int k = 0; k < 6; ++k) {
    int total = Npd[k] * Kpd[k];
    prep_w<<<(total + 255) / 256, 256, 0, stream>>>(
        (const float*)d_in[k + 1], whi[k], wlo[k], Nr[k], Kr[k], Kpd[k], total);
  }
  enc_lif0<<<(128 * 12032) / 256, 256, 0, stream>>>(img, S);
  for (int k = 0; k < 6; ++k) {
    gemm_hilo<<<dim3(Npd[k] / 128, 32), dim3(256), 0, stream>>>(
        S, whi[k], wlo[k], G, Kpd[k], Npd[k]);
    if (k < 5)
      li_lif<<<(128 * Npd[k]) / 256, 256, 0, stream>>>(G, S, Npd[k]);
  }
  final_k<<<128, 64, 0, stream>>>(G, (float*)d_out);
}